// Round 17
// baseline (1018.718 us; speedup 1.0000x reference)
//
#include <hip/hip_runtime.h>

#define H    128
#define NMQ  50000
#define NSQ  50000
#define NE   600000
#define NEL  200000
#define FIN  768
#define NLAYERS 4
#define NBLK (NSQ / 16)       // 16-row tiles per side
#define NCH  4                // source chunks (12500 rows = 3.2 MB bf16 each)
#define NK   (NSQ * NCH)      // per-(row,chunk) keys per side = 200000
#define NSCB ((NK + 1023) / 1024)

typedef __attribute__((ext_vector_type(8))) short bf16x8;
typedef __attribute__((ext_vector_type(4))) float f32x4;

__device__ inline ushort f2b(float f) {
  unsigned u = __float_as_uint(f);
  u = (u + 0x7FFFu + ((u >> 16) & 1u)) >> 16;
  return (ushort)u;
}
__device__ inline float b2f(ushort h) { return __uint_as_float((unsigned)h << 16); }

// ---------------- fp32 -> bf16 convert ----------------
__global__ void cvt_bf16(const float* __restrict__ in, ushort* __restrict__ out, int n4) {
  int i = blockIdx.x * blockDim.x + threadIdx.x;
  if (i >= n4) return;
  float4 v = ((const float4*)in)[i];
  ushort4 o;
  o.x = f2b(v.x); o.y = f2b(v.y); o.z = f2b(v.z); o.w = f2b(v.w);
  ((ushort4*)out)[i] = o;
}

// ---------------- batched weight convert ----------------
__global__ void cvt_w5(const float* __restrict__ linW,
                       const float* __restrict__ Wls, const float* __restrict__ Wrs,
                       const float* __restrict__ Wlm, const float* __restrict__ Wrm,
                       ushort* olinW, ushort* oWls, ushort* oWrs, ushort* oWlm, ushort* oWrm) {
  const float* in; ushort* out; int n4;
  switch (blockIdx.y) {
    case 0: in = linW; out = olinW; n4 = H * FIN / 4; break;
    case 1: in = Wls;  out = oWls;  n4 = NLAYERS * H * H / 4; break;
    case 2: in = Wrs;  out = oWrs;  n4 = NLAYERS * H * H / 4; break;
    case 3: in = Wlm;  out = oWlm;  n4 = NLAYERS * H * H / 4; break;
    default: in = Wrm; out = oWrm;  n4 = NLAYERS * H * H / 4; break;
  }
  int i = blockIdx.x * blockDim.x + threadIdx.x;
  if (i >= n4) return;
  float4 v = ((const float4*)in)[i];
  ushort4 o;
  o.x = f2b(v.x); o.y = f2b(v.y); o.z = f2b(v.z); o.w = f2b(v.w);
  ((ushort4*)out)[i] = o;
}

// ---------------- encoder (r3 LDS-staged form: measured 106-108 us) ----------------
__global__ __launch_bounds__(256) void encoder_mfma(
    const float* __restrict__ A, const ushort* __restrict__ Wb,
    const float* __restrict__ bias, const float* __restrict__ memb,
    ushort* __restrict__ C)
{
  __shared__ ushort As[128 * 64];   // [row][64] bf16, XOR-swizzled 16B slots
  __shared__ ushort Ws[128 * 64];
  int tid = threadIdx.x, wave = tid >> 6, lane = tid & 63;
  int rowbase = blockIdx.x * 128;
  int t = lane >> 4, fr = lane & 15;
  f32x4 acc[2][8];
  #pragma unroll
  for (int r = 0; r < 2; ++r)
    #pragma unroll
    for (int c = 0; c < 8; ++c)
      #pragma unroll
      for (int q = 0; q < 4; ++q) acc[r][c][q] = 0.f;

  for (int k0 = 0; k0 < FIN; k0 += 64) {
    #pragma unroll
    for (int i = 0; i < 4; ++i) {
      int c = tid + i * 256;
      int row = c >> 3, slot = c & 7;
      int grow = rowbase + row;
      float4 v0 = make_float4(0.f, 0.f, 0.f, 0.f), v1 = v0;
      if (grow < NSQ) {
        const float* p = A + (long)grow * FIN + k0 + slot * 8;
        v0 = *(const float4*)p;
        v1 = *(const float4*)(p + 4);
      }
      ushort tmp[8];
      tmp[0] = f2b(v0.x); tmp[1] = f2b(v0.y); tmp[2] = f2b(v0.z); tmp[3] = f2b(v0.w);
      tmp[4] = f2b(v1.x); tmp[5] = f2b(v1.y); tmp[6] = f2b(v1.z); tmp[7] = f2b(v1.w);
      *(bf16x8*)&As[row * 64 + ((slot ^ (row & 7)) << 3)] = *(bf16x8*)tmp;
    }
    #pragma unroll
    for (int i = 0; i < 4; ++i) {
      int c = tid + i * 256;
      int wrow = c >> 3, slot = c & 7;
      bf16x8 v = *(const bf16x8*)(Wb + (long)wrow * FIN + k0 + slot * 8);
      *(bf16x8*)&Ws[wrow * 64 + ((slot ^ (wrow & 7)) << 3)] = v;
    }
    __syncthreads();
    #pragma unroll
    for (int ks = 0; ks < 2; ++ks) {
      int slot = ks * 4 + t;
      bf16x8 af[2], bfm[8];
      #pragma unroll
      for (int r = 0; r < 2; ++r) {
        int row = wave * 32 + r * 16 + fr;
        af[r] = *(const bf16x8*)&As[row * 64 + ((slot ^ (row & 7)) << 3)];
      }
      #pragma unroll
      for (int cc = 0; cc < 8; ++cc) {
        int col = cc * 16 + fr;
        bfm[cc] = *(const bf16x8*)&Ws[col * 64 + ((slot ^ (col & 7)) << 3)];
      }
      #pragma unroll
      for (int r = 0; r < 2; ++r)
        #pragma unroll
        for (int cc = 0; cc < 8; ++cc)
          acc[r][cc] = __builtin_amdgcn_mfma_f32_16x16x32_bf16(af[r], bfm[cc], acc[r][cc], 0, 0, 0);
    }
    __syncthreads();
  }
  #pragma unroll
  for (int r = 0; r < 2; ++r)
    #pragma unroll
    for (int cc = 0; cc < 8; ++cc)
      #pragma unroll
      for (int q = 0; q < 4; ++q) {
        int row = rowbase + wave * 32 + r * 16 + t * 4 + q;
        if (row < NSQ) {
          int col = cc * 16 + fr;
          float v = acc[r][cc][q] + bias[col] + memb[(long)row * H + col];
          C[(long)row * H + col] = f2b(v);
        }
      }
}

// ---------------- merged fused layer: chunk-major gather for L2 locality ----------------
__global__ __launch_bounds__(64) void fused_layer2(
    const ushort* __restrict__ xmq, const ushort* __restrict__ xsq,
    const int* __restrict__ offs2_f, const int* __restrict__ csr_f,
    const int* __restrict__ drow_f,
    const int* __restrict__ offs2_r, const int* __restrict__ csr_r,
    const int* __restrict__ drow_r,
    const ushort* __restrict__ Wls, const ushort* __restrict__ Wrs,
    const float* __restrict__ bls,
    const ushort* __restrict__ Wlm, const ushort* __restrict__ Wrm,
    const float* __restrict__ blm,
    ushort* __restrict__ nsq, ushort* __restrict__ nmq, int relu)
{
  __shared__ float facc[16 * 128];    // 8 KB fp32 row accumulators
  __shared__ ushort mtile[16 * 128];  // 4 KB, 16B-slot XOR swizzle
  int side = blockIdx.x >= NBLK;
  int bidx = side ? blockIdx.x - NBLK : blockIdx.x;
  const ushort* xg    = side ? xsq     : xmq;
  const ushort* xs    = side ? xmq     : xsq;
  const int*    offs2 = side ? offs2_r : offs2_f;
  const int*    csr   = side ? csr_r   : csr_f;
  const int*    drow  = side ? drow_r  : drow_f;
  const ushort* Wl    = side ? Wlm     : Wls;
  const ushort* Wr    = side ? Wrm     : Wrs;
  const float*  bias  = side ? blm     : bls;
  ushort*       Cout  = side ? nmq     : nsq;

  int lane = threadIdx.x;
  int rowbase = bidx * 16;
  int tk = bidx * 64;                 // key base: tile*64 + chunk*16 + row
  int t = lane >> 4, fr = lane & 15;
  const unsigned* X = (const unsigned*)xg;

  // prefetch self-side A fragments (independent of gather)
  int srow = rowbase + fr;
  bf16x8 sfrag[4];
  #pragma unroll
  for (int ks = 0; ks < 4; ++ks)
    sfrag[ks] = *(const bf16x8*)(xs + (long)srow * H + (ks * 4 + t) * 8);

  // zero fp32 accumulators
  #pragma unroll
  for (int i = 0; i < 32; ++i) facc[i * 64 + lane] = 0.f;

  float a0 = 0.f, a1 = 0.f;
  int cur = -1;
#define FLUSHA() do { if (cur >= 0) {                                       \
    facc[cur * 128 + lane * 2]     += a0;                                   \
    facc[cur * 128 + lane * 2 + 1] += a1;                                   \
    a0 = 0.f; a1 = 0.f; } } while (0)

  for (int c = 0; c < NCH; ++c) {
    int js = offs2[tk + c * 16], je = offs2[tk + c * 16 + 16];
    int j = js;
    for (; j + 8 <= je; j += 8) {
      long i0 = csr[j], i1 = csr[j+1], i2 = csr[j+2], i3 = csr[j+3];
      long i4 = csr[j+4], i5 = csr[j+5], i6 = csr[j+6], i7 = csr[j+7];
      int r0 = drow[j], r1 = drow[j+1], r2 = drow[j+2], r3 = drow[j+3];
      int r4 = drow[j+4], r5 = drow[j+5], r6 = drow[j+6], r7 = drow[j+7];
      unsigned x0 = X[i0*64+lane], x1 = X[i1*64+lane], x2 = X[i2*64+lane], x3 = X[i3*64+lane];
      unsigned x4 = X[i4*64+lane], x5 = X[i5*64+lane], x6 = X[i6*64+lane], x7 = X[i7*64+lane];
      if (r0 != cur) { FLUSHA(); cur = r0; }
      a0 += b2f((ushort)(x0 & 0xffff)); a1 += b2f((ushort)(x0 >> 16));
      if (r1 != cur) { FLUSHA(); cur = r1; }
      a0 += b2f((ushort)(x1 & 0xffff)); a1 += b2f((ushort)(x1 >> 16));
      if (r2 != cur) { FLUSHA(); cur = r2; }
      a0 += b2f((ushort)(x2 & 0xffff)); a1 += b2f((ushort)(x2 >> 16));
      if (r3 != cur) { FLUSHA(); cur = r3; }
      a0 += b2f((ushort)(x3 & 0xffff)); a1 += b2f((ushort)(x3 >> 16));
      if (r4 != cur) { FLUSHA(); cur = r4; }
      a0 += b2f((ushort)(x4 & 0xffff)); a1 += b2f((ushort)(x4 >> 16));
      if (r5 != cur) { FLUSHA(); cur = r5; }
      a0 += b2f((ushort)(x5 & 0xffff)); a1 += b2f((ushort)(x5 >> 16));
      if (r6 != cur) { FLUSHA(); cur = r6; }
      a0 += b2f((ushort)(x6 & 0xffff)); a1 += b2f((ushort)(x6 >> 16));
      if (r7 != cur) { FLUSHA(); cur = r7; }
      a0 += b2f((ushort)(x7 & 0xffff)); a1 += b2f((ushort)(x7 >> 16));
    }
    for (; j < je; ++j) {
      int r = drow[j];
      unsigned x = X[(long)csr[j] * 64 + lane];
      if (r != cur) { FLUSHA(); cur = r; }
      a0 += b2f((ushort)(x & 0xffff)); a1 += b2f((ushort)(x >> 16));
    }
  }
  FLUSHA();
#undef FLUSHA

  // normalize -> swizzled bf16 mtile
  int wslot = lane >> 2;
  unsigned* mt32 = (unsigned*)mtile;
  for (int i = 0; i < 16; ++i) {
    int deg = 0;
    #pragma unroll
    for (int c = 0; c < NCH; ++c)
      deg += offs2[tk + c * 16 + i + 1] - offs2[tk + c * 16 + i];
    float inv = deg > 0 ? 1.f / (float)deg : 0.f;
    float b0 = facc[i * 128 + lane * 2] * inv;
    float b1 = facc[i * 128 + lane * 2 + 1] * inv;
    int sw = (wslot & 8) | ((wslot & 7) ^ (i & 7));
    mt32[i * 64 + sw * 4 + (lane & 3)] = (unsigned)f2b(b0) | ((unsigned)f2b(b1) << 16);
  }

  // ---- GEMM: out = mean @ Wl^T + bl + self @ Wr^T ----
  f32x4 acc[8];
  #pragma unroll
  for (int c = 0; c < 8; ++c)
    #pragma unroll
    for (int q = 0; q < 4; ++q) acc[c][q] = 0.f;

  #pragma unroll
  for (int ks = 0; ks < 4; ++ks) {
    int slot = ks * 4 + t;
    int sw = (slot & 8) | ((slot & 7) ^ (fr & 7));
    bf16x8 af = *(const bf16x8*)&mtile[fr * 128 + sw * 8];
    bf16x8 bfm[8];
    #pragma unroll
    for (int cc = 0; cc < 8; ++cc) {
      int col = cc * 16 + fr;
      bfm[cc] = *(const bf16x8*)(Wl + (long)col * H + slot * 8);
    }
    #pragma unroll
    for (int cc = 0; cc < 8; ++cc)
      acc[cc] = __builtin_amdgcn_mfma_f32_16x16x32_bf16(af, bfm[cc], acc[cc], 0, 0, 0);
  }
  #pragma unroll
  for (int ks = 0; ks < 4; ++ks) {
    int slot = ks * 4 + t;
    bf16x8 bfm[8];
    #pragma unroll
    for (int cc = 0; cc < 8; ++cc) {
      int col = cc * 16 + fr;
      bfm[cc] = *(const bf16x8*)(Wr + (long)col * H + slot * 8);
    }
    #pragma unroll
    for (int cc = 0; cc < 8; ++cc)
      acc[cc] = __builtin_amdgcn_mfma_f32_16x16x32_bf16(sfrag[ks], bfm[cc], acc[cc], 0, 0, 0);
  }
  #pragma unroll
  for (int cc = 0; cc < 8; ++cc)
    #pragma unroll
    for (int q = 0; q < 4; ++q) {
      int row = rowbase + t * 4 + q;
      int col = cc * 16 + fr;
      float v = acc[cc][q] + bias[col];
      if (relu) v = fmaxf(v, 0.f);
      Cout[(long)row * H + col] = f2b(v);
    }
}

// ---------------- degree count per (row, chunk) key ----------------
__global__ void deg_count(const int* __restrict__ eidx, int* __restrict__ d2f, int* __restrict__ d2r) {
  int e = blockIdx.x * blockDim.x + threadIdx.x;
  if (e >= NE) return;
  int s = eidx[e], d = eidx[NE + e];
  atomicAdd(d2f + ((d >> 4) * 64 + (s / 12500) * 16 + (d & 15)), 1);
  atomicAdd(d2r + ((s >> 4) * 64 + (d / 12500) * 16 + (s & 15)), 1);
}

// ---------------- 3-pass hierarchical exclusive scan over NK keys ----------------
__global__ __launch_bounds__(1024) void scan_p1(
    const int* __restrict__ d2f, const int* __restrict__ d2r,
    int* __restrict__ bsf, int* __restrict__ bsr)
{
  const int* deg = blockIdx.y ? d2r : d2f;
  int* bs = blockIdx.y ? bsr : bsf;
  __shared__ int wt[16];
  int i = blockIdx.x * 1024 + threadIdx.x;
  int d = i < NK ? deg[i] : 0;
  #pragma unroll
  for (int s = 32; s; s >>= 1) d += __shfl_down(d, s, 64);
  int wid = threadIdx.x >> 6, lane = threadIdx.x & 63;
  if (lane == 0) wt[wid] = d;
  __syncthreads();
  if (threadIdx.x == 0) {
    int s = 0;
    #pragma unroll
    for (int w = 0; w < 16; ++w) s += wt[w];
    bs[blockIdx.x] = s;
  }
}

__global__ __launch_bounds__(256) void scan_p2(
    const int* __restrict__ bsf, const int* __restrict__ bsr,
    int* __restrict__ bpf, int* __restrict__ bpr,
    int* __restrict__ offf, int* __restrict__ offr)
{
  const int* bs = blockIdx.x ? bsr : bsf;
  int* bp = blockIdx.x ? bpr : bpf;
  int* offs = blockIdx.x ? offr : offf;
  __shared__ int wt[4], wp[5];
  int tid = threadIdx.x, wid = tid >> 6, lane = tid & 63;
  int d = tid < NSCB ? bs[tid] : 0;
  int v = d;
  #pragma unroll
  for (int s = 1; s < 64; s <<= 1) { int tv = __shfl_up(v, s, 64); if (lane >= s) v += tv; }
  if (lane == 63) wt[wid] = v;
  __syncthreads();
  if (tid == 0) {
    int r = 0;
    for (int w = 0; w < 4; ++w) { wp[w] = r; r += wt[w]; }
    wp[4] = r;
  }
  __syncthreads();
  if (tid < NSCB) bp[tid] = wp[wid] + v - d;
  if (tid == 0) offs[NK] = wp[4];
}

__global__ __launch_bounds__(1024) void scan_p3(
    const int* __restrict__ d2f, const int* __restrict__ d2r,
    const int* __restrict__ bpf, const int* __restrict__ bpr,
    int* __restrict__ offf, int* __restrict__ offr)
{
  const int* deg = blockIdx.y ? d2r : d2f;
  const int* bp  = blockIdx.y ? bpr : bpf;
  int* offs = blockIdx.y ? offr : offf;
  __shared__ int wt[16], wp[17];
  int tid = threadIdx.x, wid = tid >> 6, lane = tid & 63;
  int i = blockIdx.x * 1024 + tid;
  int d = i < NK ? deg[i] : 0;
  int v = d;
  #pragma unroll
  for (int s = 1; s < 64; s <<= 1) { int tv = __shfl_up(v, s, 64); if (lane >= s) v += tv; }
  if (lane == 63) wt[wid] = v;
  __syncthreads();
  if (tid == 0) {
    int r = 0;
    for (int w = 0; w < 16; ++w) { wp[w] = r; r += wt[w]; }
    wp[16] = r;
  }
  __syncthreads();
  if (i < NK) offs[i] = bp[blockIdx.x] + wp[wid] + v - d;
}

// ---------------- keyed CSR fill (csr + local dst-row) ----------------
__global__ void csr_fill(const int* __restrict__ eidx,
                         const int* __restrict__ offs2_f, const int* __restrict__ offs2_r,
                         int* __restrict__ cur_f, int* __restrict__ cur_r,
                         int* __restrict__ csr_f, int* __restrict__ csr_r,
                         int* __restrict__ drow_f, int* __restrict__ drow_r) {
  int e = blockIdx.x * blockDim.x + threadIdx.x;
  if (e >= NE) return;
  int s = eidx[e], d = eidx[NE + e];
  int kf = (d >> 4) * 64 + (s / 12500) * 16 + (d & 15);
  int p = atomicAdd(cur_f + kf, 1);
  int pf = offs2_f[kf] + p;
  csr_f[pf] = s; drow_f[pf] = d & 15;
  int kr = (s >> 4) * 64 + (d / 12500) * 16 + (s & 15);
  int q = atomicAdd(cur_r + kr, 1);
  int pr = offs2_r[kr] + q;
  csr_r[pr] = d; drow_r[pr] = s & 15;
}

// ---------------- classifier ----------------
__global__ __launch_bounds__(256) void edge_dot_b(
    const ushort* __restrict__ xmq, const ushort* __restrict__ xsq,
    const int* __restrict__ eli, float* __restrict__ out)
{
  int wid = (blockIdx.x << 2) + (threadIdx.x >> 6);
  int lane = threadIdx.x & 63;
  if (wid >= NEL) return;
  int a = eli[wid], b = eli[NEL + wid];
  unsigned xa = ((const unsigned*)xmq)[(long)a * 64 + lane];
  unsigned xb = ((const unsigned*)xsq)[(long)b * 64 + lane];
  float p = b2f((ushort)(xa & 0xffff)) * b2f((ushort)(xb & 0xffff))
          + b2f((ushort)(xa >> 16))    * b2f((ushort)(xb >> 16));
  #pragma unroll
  for (int off = 32; off; off >>= 1) p += __shfl_down(p, off, 64);
  if (lane == 0) out[wid] = p;
}

extern "C" void kernel_launch(void* const* d_in, const int* in_sizes, int n_in,
                              void* d_out, int out_size, void* d_ws, size_t ws_size,
                              hipStream_t stream) {
  (void)in_sizes; (void)n_in; (void)out_size; (void)ws_size;
  const float* sq_x      = (const float*)d_in[2];
  const int*   eidx      = (const int*)d_in[3];
  const int*   eli       = (const int*)d_in[4];
  const float* user_emb  = (const float*)d_in[5];
  const float* movie_emb = (const float*)d_in[6];
  const float* lin_W     = (const float*)d_in[7];
  const float* lin_b     = (const float*)d_in[8];
  const float* Wl_s      = (const float*)d_in[9];
  const float* bl_s      = (const float*)d_in[10];
  const float* Wr_s      = (const float*)d_in[11];
  const float* Wl_m      = (const float*)d_in[12];
  const float* bl_m      = (const float*)d_in[13];
  const float* Wr_m      = (const float*)d_in[14];
  float* out = (float*)d_out;

  char* ws = (char*)d_ws;
  size_t off = 0;
  auto alloc = [&](size_t bytes) {
    char* p = ws + off;
    off += (bytes + 255) & ~(size_t)255;
    return p;
  };
  ushort* xmq_a = (ushort*)alloc((size_t)NMQ * H * 2);
  ushort* xmq_b = (ushort*)alloc((size_t)NMQ * H * 2);
  ushort* xsq_a = (ushort*)alloc((size_t)NSQ * H * 2);
  ushort* xsq_b = (ushort*)alloc((size_t)NSQ * H * 2);
  ushort* linWb = (ushort*)alloc((size_t)H * FIN * 2);
  ushort* Wlsb  = (ushort*)alloc((size_t)NLAYERS * H * H * 2);
  ushort* Wrsb  = (ushort*)alloc((size_t)NLAYERS * H * H * 2);
  ushort* Wlmb  = (ushort*)alloc((size_t)NLAYERS * H * H * 2);
  ushort* Wrmb  = (ushort*)alloc((size_t)NLAYERS * H * H * 2);
  int* d2_f   = (int*)alloc((size_t)NK * 4);
  int* d2_r   = (int*)alloc((size_t)NK * 4);
  int* cur_f  = (int*)alloc((size_t)NK * 4);
  int* cur_r  = (int*)alloc((size_t)NK * 4);
  int* offs2_f = (int*)alloc((size_t)(NK + 1) * 4);
  int* offs2_r = (int*)alloc((size_t)(NK + 1) * 4);
  int* bs_f   = (int*)alloc((size_t)NSCB * 4);
  int* bs_r   = (int*)alloc((size_t)NSCB * 4);
  int* bp_f   = (int*)alloc((size_t)NSCB * 4);
  int* bp_r   = (int*)alloc((size_t)NSCB * 4);
  int* csr_f  = (int*)alloc((size_t)NE * 4);
  int* csr_r  = (int*)alloc((size_t)NE * 4);
  int* drow_f = (int*)alloc((size_t)NE * 4);
  int* drow_r = (int*)alloc((size_t)NE * 4);

  // zero d2_f, d2_r, cur_f, cur_r (contiguous)
  (void)hipMemsetAsync(d2_f, 0, (char*)offs2_f - (char*)d2_f, stream);

  cvt_bf16<<<(NMQ * H / 4 + 255) / 256, 256, 0, stream>>>(user_emb, xmq_a, NMQ * H / 4);
  cvt_w5<<<dim3((H * FIN / 4 + 255) / 256, 5), 256, 0, stream>>>(
      lin_W, Wl_s, Wr_s, Wl_m, Wr_m, linWb, Wlsb, Wrsb, Wlmb, Wrmb);

  encoder_mfma<<<(NSQ + 127) / 128, 256, 0, stream>>>(sq_x, linWb, lin_b, movie_emb, xsq_a);
  deg_count<<<(NE + 255) / 256, 256, 0, stream>>>(eidx, d2_f, d2_r);
  scan_p1<<<dim3(NSCB, 2), 1024, 0, stream>>>(d2_f, d2_r, bs_f, bs_r);
  scan_p2<<<2, 256, 0, stream>>>(bs_f, bs_r, bp_f, bp_r, offs2_f, offs2_r);
  scan_p3<<<dim3(NSCB, 2), 1024, 0, stream>>>(d2_f, d2_r, bp_f, bp_r, offs2_f, offs2_r);
  csr_fill<<<(NE + 255) / 256, 256, 0, stream>>>(eidx, offs2_f, offs2_r, cur_f, cur_r,
                                                 csr_f, csr_r, drow_f, drow_r);

  ushort *cm = xmq_a, *cs = xsq_a, *nm = xmq_b, *ns = xsq_b;
  for (int l = 0; l < NLAYERS; ++l) {
    fused_layer2<<<2 * NBLK, 64, 0, stream>>>(cm, cs,
        offs2_f, csr_f, drow_f, offs2_r, csr_r, drow_r,
        Wlsb + (size_t)l * H * H, Wrsb + (size_t)l * H * H, bl_s + (size_t)l * H,
        Wlmb + (size_t)l * H * H, Wrmb + (size_t)l * H * H, bl_m + (size_t)l * H,
        ns, nm, l == 0);
    ushort* t;
    t = cm; cm = nm; nm = t;
    t = cs; cs = ns; ns = t;
  }
  edge_dot_b<<<(NEL + 3) / 4, 256, 0, stream>>>(cm, cs, eli, out);
}

// Round 19
// 658.293 us; speedup vs baseline: 1.5475x; 1.5475x over previous
//
#include <hip/hip_runtime.h>

#define H    128
#define NMQ  50000
#define NSQ  50000
#define NE   600000
#define NEL  200000
#define FIN  768
#define NLAYERS 4
#define NBLK (NSQ / 16)   // 16-row tiles per side

typedef __attribute__((ext_vector_type(8))) short bf16x8;
typedef __attribute__((ext_vector_type(4))) float f32x4;

__device__ inline ushort f2b(float f) {
  unsigned u = __float_as_uint(f);
  u = (u + 0x7FFFu + ((u >> 16) & 1u)) >> 16;
  return (ushort)u;
}
__device__ inline float b2f(ushort h) { return __uint_as_float((unsigned)h << 16); }

// ---------------- fp32 -> bf16 convert (n divisible by 4) ----------------
__global__ void cvt_bf16(const float* __restrict__ in, ushort* __restrict__ out, int n4) {
  int i = blockIdx.x * blockDim.x + threadIdx.x;
  if (i >= n4) return;
  float4 v = ((const float4*)in)[i];
  ushort4 o;
  o.x = f2b(v.x); o.y = f2b(v.y); o.z = f2b(v.z); o.w = f2b(v.w);
  ((ushort4*)out)[i] = o;
}

// ---------------- batched weight convert: 5 tensors via blockIdx.y ----------------
__global__ void cvt_w5(const float* __restrict__ linW,
                       const float* __restrict__ Wls, const float* __restrict__ Wrs,
                       const float* __restrict__ Wlm, const float* __restrict__ Wrm,
                       ushort* olinW, ushort* oWls, ushort* oWrs, ushort* oWlm, ushort* oWrm) {
  const float* in; ushort* out; int n4;
  switch (blockIdx.y) {
    case 0: in = linW; out = olinW; n4 = H * FIN / 4; break;
    case 1: in = Wls;  out = oWls;  n4 = NLAYERS * H * H / 4; break;
    case 2: in = Wrs;  out = oWrs;  n4 = NLAYERS * H * H / 4; break;
    case 3: in = Wlm;  out = oWlm;  n4 = NLAYERS * H * H / 4; break;
    default: in = Wrm; out = oWrm;  n4 = NLAYERS * H * H / 4; break;
  }
  int i = blockIdx.x * blockDim.x + threadIdx.x;
  if (i >= n4) return;
  float4 v = ((const float4*)in)[i];
  ushort4 o;
  o.x = f2b(v.x); o.y = f2b(v.y); o.z = f2b(v.z); o.w = f2b(v.w);
  ((ushort4*)out)[i] = o;
}

// ---------------- encoder (r3 LDS-staged form: measured 106-108 us) ----------------
__global__ __launch_bounds__(256) void encoder_mfma(
    const float* __restrict__ A, const ushort* __restrict__ Wb,
    const float* __restrict__ bias, const float* __restrict__ memb,
    ushort* __restrict__ C)
{
  __shared__ ushort As[128 * 64];   // [row][64] bf16, XOR-swizzled 16B slots
  __shared__ ushort Ws[128 * 64];
  int tid = threadIdx.x, wave = tid >> 6, lane = tid & 63;
  int rowbase = blockIdx.x * 128;
  int t = lane >> 4, fr = lane & 15;
  f32x4 acc[2][8];
  #pragma unroll
  for (int r = 0; r < 2; ++r)
    #pragma unroll
    for (int c = 0; c < 8; ++c)
      #pragma unroll
      for (int q = 0; q < 4; ++q) acc[r][c][q] = 0.f;

  for (int k0 = 0; k0 < FIN; k0 += 64) {
    #pragma unroll
    for (int i = 0; i < 4; ++i) {
      int c = tid + i * 256;
      int row = c >> 3, slot = c & 7;
      int grow = rowbase + row;
      float4 v0 = make_float4(0.f, 0.f, 0.f, 0.f), v1 = v0;
      if (grow < NSQ) {
        const float* p = A + (long)grow * FIN + k0 + slot * 8;
        v0 = *(const float4*)p;
        v1 = *(const float4*)(p + 4);
      }
      ushort tmp[8];
      tmp[0] = f2b(v0.x); tmp[1] = f2b(v0.y); tmp[2] = f2b(v0.z); tmp[3] = f2b(v0.w);
      tmp[4] = f2b(v1.x); tmp[5] = f2b(v1.y); tmp[6] = f2b(v1.z); tmp[7] = f2b(v1.w);
      *(bf16x8*)&As[row * 64 + ((slot ^ (row & 7)) << 3)] = *(bf16x8*)tmp;
    }
    #pragma unroll
    for (int i = 0; i < 4; ++i) {
      int c = tid + i * 256;
      int wrow = c >> 3, slot = c & 7;
      bf16x8 v = *(const bf16x8*)(Wb + (long)wrow * FIN + k0 + slot * 8);
      *(bf16x8*)&Ws[wrow * 64 + ((slot ^ (wrow & 7)) << 3)] = v;
    }
    __syncthreads();
    #pragma unroll
    for (int ks = 0; ks < 2; ++ks) {
      int slot = ks * 4 + t;
      bf16x8 af[2], bfm[8];
      #pragma unroll
      for (int r = 0; r < 2; ++r) {
        int row = wave * 32 + r * 16 + fr;
        af[r] = *(const bf16x8*)&As[row * 64 + ((slot ^ (row & 7)) << 3)];
      }
      #pragma unroll
      for (int cc = 0; cc < 8; ++cc) {
        int col = cc * 16 + fr;
        bfm[cc] = *(const bf16x8*)&Ws[col * 64 + ((slot ^ (col & 7)) << 3)];
      }
      #pragma unroll
      for (int r = 0; r < 2; ++r)
        #pragma unroll
        for (int cc = 0; cc < 8; ++cc)
          acc[r][cc] = __builtin_amdgcn_mfma_f32_16x16x32_bf16(af[r], bfm[cc], acc[r][cc], 0, 0, 0);
    }
    __syncthreads();
  }
  #pragma unroll
  for (int r = 0; r < 2; ++r)
    #pragma unroll
    for (int cc = 0; cc < 8; ++cc)
      #pragma unroll
      for (int q = 0; q < 4; ++q) {
        int row = rowbase + wave * 32 + r * 16 + t * 4 + q;
        if (row < NSQ) {
          int col = cc * 16 + fr;
          float v = acc[r][cc][q] + bias[col] + memb[(long)row * H + col];
          C[(long)row * H + col] = f2b(v);
        }
      }
}

// ---------------- merged both-sides fused SpMM-mean + SAGE GEMM (r9/r15 form) ----------------
__global__ __launch_bounds__(64) void fused_layer2(
    const ushort* __restrict__ xmq, const ushort* __restrict__ xsq,
    const int* __restrict__ offs_f, const int* __restrict__ csr_f,
    const int* __restrict__ offs_r, const int* __restrict__ csr_r,
    const ushort* __restrict__ Wls, const ushort* __restrict__ Wrs,
    const float* __restrict__ bls,
    const ushort* __restrict__ Wlm, const ushort* __restrict__ Wrm,
    const float* __restrict__ blm,
    ushort* __restrict__ nsq, ushort* __restrict__ nmq, int relu)
{
  __shared__ ushort mtile[16 * 128];  // 4 KB, 16B-slot XOR swizzle
  int side = blockIdx.x >= NBLK;
  int bidx = side ? blockIdx.x - NBLK : blockIdx.x;
  const ushort* xg   = side ? xsq    : xmq;
  const ushort* xs   = side ? xmq    : xsq;
  const int*    offs = side ? offs_r : offs_f;
  const int*    csr  = side ? csr_r  : csr_f;
  const ushort* Wl   = side ? Wlm    : Wls;
  const ushort* Wr   = side ? Wrm    : Wrs;
  const float*  bias = side ? blm    : bls;
  ushort*       Cout = side ? nmq    : nsq;

  int lane = threadIdx.x;
  int rowbase = bidx * 16;
  int t = lane >> 4, fr = lane & 15;
  const unsigned* X = (const unsigned*)xg;

  // prefetch self-side A fragments (independent of gather)
  int srow = rowbase + fr;
  bf16x8 sfrag[4];
  #pragma unroll
  for (int ks = 0; ks < 4; ++ks)
    sfrag[ks] = *(const bf16x8*)(xs + (long)srow * H + (ks * 4 + t) * 8);

  // ---- phase 1: means (register gather, 8-deep) ----
  int wslot = lane >> 2;
  unsigned* mt32 = (unsigned*)mtile;
  for (int i = 0; i < 16; ++i) {
    int row = rowbase + i;
    int s = offs[row], e = offs[row + 1];
    float a0 = 0.f, a1 = 0.f;
    int j = s;
    for (; j + 8 <= e; j += 8) {
      long i0 = csr[j], i1 = csr[j+1], i2 = csr[j+2], i3 = csr[j+3];
      long i4 = csr[j+4], i5 = csr[j+5], i6 = csr[j+6], i7 = csr[j+7];
      unsigned x0 = X[i0*64+lane], x1 = X[i1*64+lane], x2 = X[i2*64+lane], x3 = X[i3*64+lane];
      unsigned x4 = X[i4*64+lane], x5 = X[i5*64+lane], x6 = X[i6*64+lane], x7 = X[i7*64+lane];
      a0 += b2f((ushort)(x0 & 0xffff)) + b2f((ushort)(x1 & 0xffff))
          + b2f((ushort)(x2 & 0xffff)) + b2f((ushort)(x3 & 0xffff))
          + b2f((ushort)(x4 & 0xffff)) + b2f((ushort)(x5 & 0xffff))
          + b2f((ushort)(x6 & 0xffff)) + b2f((ushort)(x7 & 0xffff));
      a1 += b2f((ushort)(x0 >> 16)) + b2f((ushort)(x1 >> 16))
          + b2f((ushort)(x2 >> 16)) + b2f((ushort)(x3 >> 16))
          + b2f((ushort)(x4 >> 16)) + b2f((ushort)(x5 >> 16))
          + b2f((ushort)(x6 >> 16)) + b2f((ushort)(x7 >> 16));
    }
    if (j + 4 <= e) {
      long i0 = csr[j], i1 = csr[j+1], i2 = csr[j+2], i3 = csr[j+3];
      unsigned x0 = X[i0*64+lane], x1 = X[i1*64+lane], x2 = X[i2*64+lane], x3 = X[i3*64+lane];
      a0 += b2f((ushort)(x0 & 0xffff)) + b2f((ushort)(x1 & 0xffff))
          + b2f((ushort)(x2 & 0xffff)) + b2f((ushort)(x3 & 0xffff));
      a1 += b2f((ushort)(x0 >> 16)) + b2f((ushort)(x1 >> 16))
          + b2f((ushort)(x2 >> 16)) + b2f((ushort)(x3 >> 16));
      j += 4;
    }
    for (; j < e; ++j) {
      unsigned x = X[(long)csr[j] * 64 + lane];
      a0 += b2f((ushort)(x & 0xffff));
      a1 += b2f((ushort)(x >> 16));
    }
    float inv = (e > s) ? 1.f / (float)(e - s) : 0.f;
    a0 *= inv; a1 *= inv;
    int sw = (wslot & 8) | ((wslot & 7) ^ (i & 7));
    mt32[i * 64 + sw * 4 + (lane & 3)] = (unsigned)f2b(a0) | ((unsigned)f2b(a1) << 16);
  }
  // wave-local LDS: no barrier needed (one wave per block)

  // ---- phase 2: GEMM ----
  f32x4 acc[8];
  #pragma unroll
  for (int c = 0; c < 8; ++c)
    #pragma unroll
    for (int q = 0; q < 4; ++q) acc[c][q] = 0.f;

  // mean side (A from LDS), K = 128
  #pragma unroll
  for (int ks = 0; ks < 4; ++ks) {
    int slot = ks * 4 + t;
    int sw = (slot & 8) | ((slot & 7) ^ (fr & 7));
    bf16x8 af = *(const bf16x8*)&mtile[fr * 128 + sw * 8];
    bf16x8 bfm[8];
    #pragma unroll
    for (int cc = 0; cc < 8; ++cc) {
      int col = cc * 16 + fr;
      bfm[cc] = *(const bf16x8*)(Wl + (long)col * H + slot * 8);
    }
    #pragma unroll
    for (int cc = 0; cc < 8; ++cc)
      acc[cc] = __builtin_amdgcn_mfma_f32_16x16x32_bf16(af, bfm[cc], acc[cc], 0, 0, 0);
  }
  // self side (A prefetched in registers), K = 128
  #pragma unroll
  for (int ks = 0; ks < 4; ++ks) {
    int slot = ks * 4 + t;
    bf16x8 bfm[8];
    #pragma unroll
    for (int cc = 0; cc < 8; ++cc) {
      int col = cc * 16 + fr;
      bfm[cc] = *(const bf16x8*)(Wr + (long)col * H + slot * 8);
    }
    #pragma unroll
    for (int cc = 0; cc < 8; ++cc)
      acc[cc] = __builtin_amdgcn_mfma_f32_16x16x32_bf16(sfrag[ks], bfm[cc], acc[cc], 0, 0, 0);
  }
  // epilogue
  #pragma unroll
  for (int cc = 0; cc < 8; ++cc)
    #pragma unroll
    for (int q = 0; q < 4; ++q) {
      int row = rowbase + t * 4 + q;
      int col = cc * 16 + fr;
      float v = acc[cc][q] + bias[col];
      if (relu) v = fmaxf(v, 0.f);
      Cout[(long)row * H + col] = f2b(v);
    }
}

// ---------------- degree count ----------------
__global__ void deg_count(const int* __restrict__ eidx, int* __restrict__ df, int* __restrict__ dr) {
  int e = blockIdx.x * blockDim.x + threadIdx.x;
  if (e >= NE) return;
  atomicAdd(dr + eidx[e], 1);
  atomicAdd(df + eidx[NE + e], 1);
}

// ---------------- coalesced dual exclusive scan (r15 form) ----------------
__global__ __launch_bounds__(1024) void exscan2(
    const int* __restrict__ degf, const int* __restrict__ degr,
    int* __restrict__ offf, int* __restrict__ offr)
{
  __shared__ int wtot[16], wpre[17];
  const int* deg = blockIdx.x ? degr : degf;
  int* offs = blockIdx.x ? offr : offf;
  int n = blockIdx.x ? NMQ : NSQ;
  int tid = threadIdx.x, wid = tid >> 6, lane = tid & 63;
  int carry = 0;
  for (int base = 0; base < n; base += 1024) {
    int i = base + tid;
    int d = (i < n) ? deg[i] : 0;
    int v = d;
    #pragma unroll
    for (int s = 1; s < 64; s <<= 1) {
      int tv = __shfl_up(v, s, 64);
      if (lane >= s) v += tv;
    }
    if (lane == 63) wtot[wid] = v;
    __syncthreads();
    if (tid == 0) {
      int run = 0;
      #pragma unroll
      for (int w = 0; w < 16; ++w) { wpre[w] = run; run += wtot[w]; }
      wpre[16] = run;
    }
    __syncthreads();
    if (i < n) offs[i] = carry + wpre[wid] + v - d;
    carry += wpre[16];
  }
  if (tid == 0) offs[n] = carry;
}

// ---------------- CSR fill ----------------
__global__ void csr_fill(const int* __restrict__ eidx,
                         const int* __restrict__ offs_f, const int* __restrict__ offs_r,
                         int* __restrict__ cur_f, int* __restrict__ cur_r,
                         int* __restrict__ csr_f, int* __restrict__ csr_r) {
  int e = blockIdx.x * blockDim.x + threadIdx.x;
  if (e >= NE) return;
  int s = eidx[e], d = eidx[NE + e];
  int p = atomicAdd(cur_f + d, 1); csr_f[offs_f[d] + p] = s;
  int q = atomicAdd(cur_r + s, 1); csr_r[offs_r[s] + q] = d;
}

// ---------------- classifier: one wave per label edge ----------------
__global__ __launch_bounds__(256) void edge_dot_b(
    const ushort* __restrict__ xmq, const ushort* __restrict__ xsq,
    const int* __restrict__ eli, float* __restrict__ out)
{
  int wid = (blockIdx.x << 2) + (threadIdx.x >> 6);
  int lane = threadIdx.x & 63;
  if (wid >= NEL) return;
  int a = eli[wid], b = eli[NEL + wid];
  unsigned xa = ((const unsigned*)xmq)[(long)a * 64 + lane];
  unsigned xb = ((const unsigned*)xsq)[(long)b * 64 + lane];
  float p = b2f((ushort)(xa & 0xffff)) * b2f((ushort)(xb & 0xffff))
          + b2f((ushort)(xa >> 16))    * b2f((ushort)(xb >> 16));
  #pragma unroll
  for (int off = 32; off; off >>= 1) p += __shfl_down(p, off, 64);
  if (lane == 0) out[wid] = p;
}

extern "C" void kernel_launch(void* const* d_in, const int* in_sizes, int n_in,
                              void* d_out, int out_size, void* d_ws, size_t ws_size,
                              hipStream_t stream) {
  (void)in_sizes; (void)n_in; (void)out_size; (void)ws_size;
  // d_in[0]=mq_node_id (arange, unused), d_in[1]=sq_node_id (arange, unused)
  const float* sq_x      = (const float*)d_in[2];
  const int*   eidx      = (const int*)d_in[3];
  const int*   eli       = (const int*)d_in[4];
  const float* user_emb  = (const float*)d_in[5];
  const float* movie_emb = (const float*)d_in[6];
  const float* lin_W     = (const float*)d_in[7];
  const float* lin_b     = (const float*)d_in[8];
  const float* Wl_s      = (const float*)d_in[9];
  const float* bl_s      = (const float*)d_in[10];
  const float* Wr_s      = (const float*)d_in[11];
  const float* Wl_m      = (const float*)d_in[12];
  const float* bl_m      = (const float*)d_in[13];
  const float* Wr_m      = (const float*)d_in[14];
  float* out = (float*)d_out;

  char* ws = (char*)d_ws;
  size_t off = 0;
  auto alloc = [&](size_t bytes) {
    char* p = ws + off;
    off += (bytes + 255) & ~(size_t)255;
    return p;
  };
  ushort* xmq_a = (ushort*)alloc((size_t)NMQ * H * 2);
  ushort* xmq_b = (ushort*)alloc((size_t)NMQ * H * 2);
  ushort* xsq_a = (ushort*)alloc((size_t)NSQ * H * 2);
  ushort* xsq_b = (ushort*)alloc((size_t)NSQ * H * 2);
  ushort* linWb = (ushort*)alloc((size_t)H * FIN * 2);
  ushort* Wlsb  = (ushort*)alloc((size_t)NLAYERS * H * H * 2);
  ushort* Wrsb  = (ushort*)alloc((size_t)NLAYERS * H * H * 2);
  ushort* Wlmb  = (ushort*)alloc((size_t)NLAYERS * H * H * 2);
  ushort* Wrmb  = (ushort*)alloc((size_t)NLAYERS * H * H * 2);
  int* deg_f  = (int*)alloc((size_t)NSQ * 4);
  int* deg_r  = (int*)alloc((size_t)NMQ * 4);
  int* cur_f  = (int*)alloc((size_t)NSQ * 4);
  int* cur_r  = (int*)alloc((size_t)NMQ * 4);
  int* offs_f = (int*)alloc((size_t)(NSQ + 1) * 4);
  int* offs_r = (int*)alloc((size_t)(NMQ + 1) * 4);
  int* csr_f  = (int*)alloc((size_t)NE * 4);
  int* csr_r  = (int*)alloc((size_t)NE * 4);

  (void)hipMemsetAsync(deg_f, 0, (char*)offs_f - (char*)deg_f, stream);

  // conversions (2 launches: embeddings + batched weights)
  cvt_bf16<<<(NMQ * H / 4 + 255) / 256, 256, 0, stream>>>(user_emb, xmq_a, NMQ * H / 4);
  cvt_w5<<<dim3((H * FIN / 4 + 255) / 256, 5), 256, 0, stream>>>(
      lin_W, Wl_s, Wr_s, Wl_m, Wr_m, linWb, Wlsb, Wrsb, Wlmb, Wrmb);

  encoder_mfma<<<(NSQ + 127) / 128, 256, 0, stream>>>(sq_x, linWb, lin_b, movie_emb, xsq_a);
  deg_count<<<(NE + 255) / 256, 256, 0, stream>>>(eidx, deg_f, deg_r);
  exscan2<<<2, 1024, 0, stream>>>(deg_f, deg_r, offs_f, offs_r);
  csr_fill<<<(NE + 255) / 256, 256, 0, stream>>>(eidx, offs_f, offs_r, cur_f, cur_r, csr_f, csr_r);

  ushort *cm = xmq_a, *cs = xsq_a, *nm = xmq_b, *ns = xsq_b;
  for (int l = 0; l < NLAYERS; ++l) {
    fused_layer2<<<2 * NBLK, 64, 0, stream>>>(cm, cs, offs_f, csr_f, offs_r, csr_r,
        Wlsb + (size_t)l * H * H, Wrsb + (size_t)l * H * H, bl_s + (size_t)l * H,
        Wlmb + (size_t)l * H * H, Wrmb + (size_t)l * H * H, bl_m + (size_t)l * H,
        ns, nm, l == 0);
    ushort* t;
    t = cm; cm = nm; nm = t;
    t = cs; cs = ns; ns = t;
  }
  edge_dot_b<<<(NEL + 3) / 4, 256, 0, stream>>>(cm, cs, eli, out);
}